// Round 12
// baseline (140.389 us; speedup 1.0000x reference)
//
#include <hip/hip_runtime.h>

#define B 16384
#define N_SPARSE 16
#define N_VARLEN 4
#define L 50
#define V 1000000
#define ROW (N_SPARSE + N_VARLEN * L)   // 216 ids per row
#define OUT_W (N_SPARSE + N_VARLEN)     // 20 floats per row
#define KLANES 8                        // lanes cooperating per (row, varlen feature)

// Model (R1-R9): bound by per-CU divergent-gather request cost (~4.8 cy/lane
// request even L2-resident). Bytes ruled out (R1 demand path sustained
// 3.2 TB/s; we fetch at 1.4), MSHR/ILP/occupancy/warming all neutral.
// Last untested mechanism: L1 line allocation per divergent request (random
// gathers thrash the 32KB L1; each request pays tag-allocate + 64B fill).
// THIS ROUND (single change vs R8): varlen gathers use non-temporal loads
// (no L1 allocation). Sparse was already nt.
#define VARLEN_BLOCKS 2048
#define SPARSE_BLOCKS 1024

typedef int v2i __attribute__((ext_vector_type(2)));

__global__ __launch_bounds__(256) void emb_gather_pool_kernel(
    const int* __restrict__ X,
    const float* __restrict__ sparse_tables,
    const float* __restrict__ varlen_tables,
    float* __restrict__ out)
{
    const int bid = blockIdx.x;
    const int t   = threadIdx.x;

    if (bid < VARLEN_BLOCKS) {
        // ---- varlen masked-mean pooling, XCD-pinned per table ----
        const int xcd  = bid & 7;
        const int f    = xcd & 3;        // table f on XCDs f and f+4
        const int half = xcd >> 2;       // which half of the rows
        const int slot = bid >> 3;       // [0,256) row-chunk within (f, half)
        const int task = t >> 3;         // [0,32) row within block
        const int lane = t & (KLANES - 1);
        const int row  = half * (B / 2) + slot * 32 + task;

        const int*   ids = X + row * ROW + N_SPARSE + f * L;
        const float* tab = varlen_tables + (long)f * V;

        // Phase 1: id loads. 3x 8B vector loads cover ids 0..47 (8B-aligned);
        // tail 48+lane for lanes 0..1; others id=0 (nullified by mask -> exact).
        int id[7];
        #pragma unroll
        for (int k = 0; k < 3; ++k) {
            const v2i w = __builtin_nontemporal_load(
                reinterpret_cast<const v2i*>(ids + 2 * lane + 16 * k));
            id[2 * k]     = w.x;
            id[2 * k + 1] = w.y;
        }
        id[6] = (lane < 2) ? __builtin_nontemporal_load(ids + 48 + lane) : 0;

        // Phase 2: gathers, NON-TEMPORAL (no L1 line allocation; L2 still
        // serves the 13x line reuse). Slot 6 exec-predicated (no OOB traffic).
        float v[7];
        #pragma unroll
        for (int k = 0; k < 6; ++k) {
            v[k] = __builtin_nontemporal_load(tab + id[k]);
        }
        v[6] = 0.0f;
        if (lane < 2) {
            v[6] = __builtin_nontemporal_load(tab + id[6]);
        }

        // Phase 3: branch-free masked accumulate.
        float sum = 0.0f;
        float cnt = 0.0f;
        #pragma unroll
        for (int k = 0; k < 7; ++k) {
            const float m = (id[k] != 0) ? 1.0f : 0.0f;
            sum = fmaf(m, v[k], sum);
            cnt += m;
        }

        // Reduce across the aligned 8-lane group.
        #pragma unroll
        for (int off = 1; off < KLANES; off <<= 1) {
            sum += __shfl_xor(sum, off);
            cnt += __shfl_xor(cnt, off);
        }

        if (lane == 0) {
            __builtin_nontemporal_store(sum / (cnt + 1e-8f),
                                        out + row * OUT_W + N_SPARSE + f);
        }
    } else {
        // ---- sparse single gathers, fully streaming (non-temporal) ----
        const int sb  = bid - VARLEN_BLOCKS;   // [0,1024)
        const int rl  = t >> 4;                // row within block [0,16)
        const int j   = t & 15;                // sparse feature
        const int row = sb * 16 + rl;

        const int   id = __builtin_nontemporal_load(X + row * ROW + j);
        const float v  = __builtin_nontemporal_load(sparse_tables + (long)j * V + id);
        __builtin_nontemporal_store(v, out + row * OUT_W + j);
    }
}

extern "C" void kernel_launch(void* const* d_in, const int* in_sizes, int n_in,
                              void* d_out, int out_size, void* d_ws, size_t ws_size,
                              hipStream_t stream) {
    const int*   X             = (const int*)  d_in[0];
    const float* sparse_tables = (const float*)d_in[1];
    const float* varlen_tables = (const float*)d_in[2];
    float*       out           = (float*)d_out;

    const int grid  = VARLEN_BLOCKS + SPARSE_BLOCKS;   // 3072
    const int block = 256;

    emb_gather_pool_kernel<<<grid, block, 0, stream>>>(X, sparse_tables, varlen_tables, out);
}

// Round 14
// 126.185 us; speedup vs baseline: 1.1126x; 1.1126x over previous
//
#include <hip/hip_runtime.h>

#define B 16384
#define N_SPARSE 16
#define N_VARLEN 4
#define L 50
#define V 1000000
#define ROW (N_SPARSE + N_VARLEN * L)   // 216 ids per row
#define OUT_W (N_SPARSE + N_VARLEN)     // 20 floats per row
#define KLANES 8                        // lanes cooperating per (row, varlen feature)

// FINAL MODEL (R1-R12): bound by per-CU divergent-gather request cost
// (~5-6 cy/lane-request, L1/TCP outstanding-capacity x L2-hit latency).
// Ruled out: bytes (R5: 47MB = compulsory floor), wave-ILP (R4), MLP depth
// (R6), atomic work-pool (R5: 2x worse), L2 pre-warming (R9: neutral,
// tables self-warm under 13x reuse), L1 bypass via nt gathers (R12: -25%,
// nt breaks pinned-table L2 residency: FETCH 47->65MB).
// Winning ingredients: XCD-pinned varlen tables (bid&7 -> table f=bid&3,
// 184->47MB refetch), nt for streaming-only data (X, sparse, out),
// vectorized id loads, exec-predicated exact-50 gathers.
#define VARLEN_BLOCKS 2048
#define SPARSE_BLOCKS 1024

typedef int v2i __attribute__((ext_vector_type(2)));

__global__ __launch_bounds__(256) void emb_gather_pool_kernel(
    const int* __restrict__ X,
    const float* __restrict__ sparse_tables,
    const float* __restrict__ varlen_tables,
    float* __restrict__ out)
{
    const int bid = blockIdx.x;
    const int t   = threadIdx.x;

    if (bid < VARLEN_BLOCKS) {
        // ---- varlen masked-mean pooling, XCD-pinned per table ----
        const int xcd  = bid & 7;
        const int f    = xcd & 3;        // table f on XCDs f and f+4
        const int half = xcd >> 2;       // which half of the rows
        const int slot = bid >> 3;       // [0,256) row-chunk within (f, half)
        const int task = t >> 3;         // [0,32) row within block
        const int lane = t & (KLANES - 1);
        const int row  = half * (B / 2) + slot * 32 + task;

        const int*   ids = X + row * ROW + N_SPARSE + f * L;
        const float* tab = varlen_tables + (long)f * V;

        // Phase 1: id loads. 3x 8B vector loads cover ids 0..47 (8B-aligned);
        // tail 48+lane for lanes 0..1; others id=0 (nullified by mask -> exact).
        int id[7];
        #pragma unroll
        for (int k = 0; k < 3; ++k) {
            const v2i w = __builtin_nontemporal_load(
                reinterpret_cast<const v2i*>(ids + 2 * lane + 16 * k));
            id[2 * k]     = w.x;
            id[2 * k + 1] = w.y;
        }
        id[6] = (lane < 2) ? __builtin_nontemporal_load(ids + 48 + lane) : 0;

        // Phase 2: gathers via NORMAL cached loads (lines stay in this XCD's
        // L2, 13x reuse). Slot 6 exec-predicated: exactly 50 transactions.
        float v[7];
        #pragma unroll
        for (int k = 0; k < 6; ++k) {
            v[k] = tab[id[k]];
        }
        v[6] = 0.0f;
        if (lane < 2) {
            v[6] = tab[id[6]];
        }

        // Phase 3: branch-free masked accumulate.
        float sum = 0.0f;
        float cnt = 0.0f;
        #pragma unroll
        for (int k = 0; k < 7; ++k) {
            const float m = (id[k] != 0) ? 1.0f : 0.0f;
            sum = fmaf(m, v[k], sum);
            cnt += m;
        }

        // Reduce across the aligned 8-lane group.
        #pragma unroll
        for (int off = 1; off < KLANES; off <<= 1) {
            sum += __shfl_xor(sum, off);
            cnt += __shfl_xor(cnt, off);
        }

        if (lane == 0) {
            __builtin_nontemporal_store(sum / (cnt + 1e-8f),
                                        out + row * OUT_W + N_SPARSE + f);
        }
    } else {
        // ---- sparse single gathers, fully streaming (non-temporal) ----
        const int sb  = bid - VARLEN_BLOCKS;   // [0,1024)
        const int rl  = t >> 4;                // row within block [0,16)
        const int j   = t & 15;                // sparse feature
        const int row = sb * 16 + rl;

        const int   id = __builtin_nontemporal_load(X + row * ROW + j);
        const float v  = __builtin_nontemporal_load(sparse_tables + (long)j * V + id);
        __builtin_nontemporal_store(v, out + row * OUT_W + j);
    }
}

extern "C" void kernel_launch(void* const* d_in, const int* in_sizes, int n_in,
                              void* d_out, int out_size, void* d_ws, size_t ws_size,
                              hipStream_t stream) {
    const int*   X             = (const int*)  d_in[0];
    const float* sparse_tables = (const float*)d_in[1];
    const float* varlen_tables = (const float*)d_in[2];
    float*       out           = (float*)d_out;

    const int grid  = VARLEN_BLOCKS + SPARSE_BLOCKS;   // 3072
    const int block = 256;

    emb_gather_pool_kernel<<<grid, block, 0, stream>>>(X, sparse_tables, varlen_tables, out);
}